// Round 1
// 383.543 us; speedup vs baseline: 1.0015x; 1.0015x over previous
//
#include <hip/hip_runtime.h>

// UWNeRF RGB renderer: R rays x S=128 samples, fp32.
// 32 lanes per ray (2 rays per wave), lane owns 4 contiguous samples.
// R2: cross-lane scan + reduction moved off the DS pipe onto VALU DPP ops.
//   scan:      row_shr:1/2/4/8 + row_bcast15  (5 DPP rounds, 0 DS ops)
//   butterfly: quad_perm xor1/xor2 + row_half_mirror(xor4) + row_mirror
//              (acts as xor8 on 8-group-uniform values) + one ds_swizzle xor16
//   veil[s=0] broadcast folded into the butterfly as 3 extra values.
// DS ops/thread: 88 -> 13; dependent cross-lane chain ~10x100cy -> ~10x8cy.
// (R1 evidence: VALUBusy 17%, HBM 20%, MfmaUtil 0, occupancy 69% -- nothing
// saturated => latency-bound on the dependent ds_bpermute rounds.)

constexpr int S = 128;

// x + dpp(x) with compile-time DPP control; old=0 so masked rows add identity.
template<int CTRL, int RM, bool BC>
__device__ __forceinline__ float dpp_add(float x) {
    const int t = __builtin_amdgcn_update_dpp(0, __float_as_int(x), CTRL, RM, 0xF, BC);
    return x + __int_as_float(t);
}

// x + lane(x ^ 16) via ds_swizzle (BitMode xor=16: 0x401F)
__device__ __forceinline__ float swz16_add(float x) {
    const int t = __builtin_amdgcn_ds_swizzle(__float_as_int(x), 0x401F);
    return x + __int_as_float(t);
}

__global__ __launch_bounds__(256) void uwnerf_render(
    const float* __restrict__ densities,   // [R,S,1]
    const float* __restrict__ rgbs,        // [R,S,3]
    const float* __restrict__ veil,        // [R,S,3]
    const float* __restrict__ dcoef,       // [R,S,3]
    const float* __restrict__ bcoef,       // [R,S,3]
    const float* __restrict__ deltas,      // [R,S,1]
    float* __restrict__ out,               // [4,R,3]: rgb, restored, direct, backscatter
    int R)
{
    const int lane = threadIdx.x & 63;
    const int l = lane & 31;          // lane within ray
    const int r = blockIdx.x * 8 + (int)(threadIdx.x >> 6) * 2 + (lane >> 5);
    if (r >= R) return;

    const size_t b1 = (size_t)r * S + 4 * (size_t)l;   // scalar arrays, 16B/lane
    const size_t b3 = b1 * 3;                          // channel arrays, 48B/lane (16B-aligned)

    const float4 den4 = *(const float4*)(densities + b1);
    const float4 dlt4 = *(const float4*)(deltas + b1);

    float rgbv[12], vlv[12], dcv[12], bcv[12];
#pragma unroll
    for (int i = 0; i < 3; ++i) {
        *(float4*)(rgbv + 4 * i) = *(const float4*)(rgbs  + b3 + 4 * i);
        *(float4*)(vlv  + 4 * i) = *(const float4*)(veil  + b3 + 4 * i);
        *(float4*)(dcv  + 4 * i) = *(const float4*)(dcoef + b3 + 4 * i);
        *(float4*)(bcv  + 4 * i) = *(const float4*)(bcoef + b3 + 4 * i);
    }

    const float dl[4] = {dlt4.x, dlt4.y, dlt4.z, dlt4.w};
    const float dn[4] = {den4.x, den4.y, den4.z, den4.w};

    // local exclusive prefixes (per-lane, in registers)
    float odd[4], cumO[4];
    float accO = 0.0f;
#pragma unroll
    for (int s = 0; s < 4; ++s) {
        odd[s] = dl[s] * dn[s];
        cumO[s] = accO;
        accO += odd[s];
    }

    float cumD[12], cumB[12], loc[7];
    loc[0] = accO;
#pragma unroll
    for (int c = 0; c < 3; ++c) {
        float ad = 0.0f, ab = 0.0f;
#pragma unroll
        for (int s = 0; s < 4; ++s) {
            const float dv = dl[s] * dcv[3 * s + c];
            const float bv = dl[s] * bcv[3 * s + c];
            cumD[4 * c + s] = ad; ad += dv;
            cumB[4 * c + s] = ab; ab += bv;
        }
        loc[1 + c] = ad;
        loc[4 + c] = ab;
    }

    // inclusive scan of 7 lane-aggregates within each 32-lane half — DPP (VALU pipe)
    float agg[7];
#pragma unroll
    for (int j = 0; j < 7; ++j) agg[j] = loc[j];
#pragma unroll
    for (int j = 0; j < 7; ++j) agg[j] = dpp_add<0x111, 0xF, true>(agg[j]);  // row_shr:1
#pragma unroll
    for (int j = 0; j < 7; ++j) agg[j] = dpp_add<0x112, 0xF, true>(agg[j]);  // row_shr:2
#pragma unroll
    for (int j = 0; j < 7; ++j) agg[j] = dpp_add<0x114, 0xF, true>(agg[j]);  // row_shr:4
#pragma unroll
    for (int j = 0; j < 7; ++j) agg[j] = dpp_add<0x118, 0xF, true>(agg[j]);  // row_shr:8
#pragma unroll
    for (int j = 0; j < 7; ++j) agg[j] = dpp_add<0x142, 0xA, false>(agg[j]); // row_bcast15 -> rows 1,3

    float Lex[7];  // exclusive lane prefix
#pragma unroll
    for (int j = 0; j < 7; ++j) Lex[j] = agg[j] - loc[j];

    // object transmittance / weights
    float t_[4], T_[4], w_[4];
    const float TL = __expf(-Lex[0]);
#pragma unroll
    for (int s = 0; s < 4; ++s) t_[s] = __expf(-odd[s]);
    T_[0] = TL;
#pragma unroll
    for (int s = 1; s < 4; ++s) T_[s] = T_[s - 1] * t_[s - 1];
#pragma unroll
    for (int s = 0; s < 4; ++s) w_[s] = (1.0f - t_[s]) * T_[s];

    // partial reductions: [0..2] restored, [3..5] direct, [6..8] backscatter_obj,
    // [9] wsum, [10..12] veil[s=0] broadcast (only lane 0 contributes)
    float red[13];
    red[9] = w_[0] + w_[1] + w_[2] + w_[3];
#pragma unroll
    for (int c = 0; c < 3; ++c) {
        const float BD = Lex[0] + Lex[1 + c];
        const float BB = Lex[0] + Lex[4 + c];
        float sr = 0.0f, sd = 0.0f, sb = 0.0f;
#pragma unroll
        for (int s = 0; s < 4; ++s) {
            const float g = rgbv[3 * s + c];
            const float v = vlv[3 * s + c];
            const float omt = 1.0f - t_[s];
            // w_s * direct_atten = (1-t_s) * exp(-(exO_s + exD_s))
            const float wda = omt * __expf(-(BD + cumO[s] + cumD[4 * c + s]));
            // w_s * backscatter_transmittance
            const float wbt = omt * __expf(-(BB + cumO[s] + cumB[4 * c + s]));
            sr += w_[s] * g;
            sd += wda * g;
            sb += (w_[s] - wbt) * v;
        }
        red[c] = sr;
        red[3 + c] = sd;
        red[6 + c] = sb;
        red[10 + c] = (l == 0) ? vlv[c] : 0.0f;
    }

    // butterfly reduction within each 32-lane half — DPP + one ds_swizzle hop.
    // After xor1/xor2 values are 4-group-uniform -> half_mirror (xor7) acts as
    // xor4; after that 8-group-uniform -> mirror (xor15) acts as xor8.
#pragma unroll
    for (int j = 0; j < 13; ++j) red[j] = dpp_add<0xB1, 0xF, false>(red[j]);  // quad_perm(1,0,3,2): xor1
#pragma unroll
    for (int j = 0; j < 13; ++j) red[j] = dpp_add<0x4E, 0xF, false>(red[j]);  // quad_perm(2,3,0,1): xor2
#pragma unroll
    for (int j = 0; j < 13; ++j) red[j] = dpp_add<0x141, 0xF, false>(red[j]); // row_half_mirror: xor4
#pragma unroll
    for (int j = 0; j < 13; ++j) red[j] = dpp_add<0x140, 0xF, false>(red[j]); // row_mirror: xor8-equiv
#pragma unroll
    for (int j = 0; j < 13; ++j) red[j] = swz16_add(red[j]);                  // xor16

    if (l < 3) {
        const int c = l;
        const float mask = fminf(fmaxf(red[9], 0.0f), 1.0f);
        const float bsr  = red[6 + c] + (1.0f - mask) * red[10 + c];
        const size_t rc = (size_t)r * 3 + c;
        const size_t stride = (size_t)R * 3;
        out[rc]              = fminf(fmaxf(red[3 + c] + bsr, 0.0f), 1.0f); // rgb
        out[stride + rc]     = fminf(fmaxf(red[c],          0.0f), 1.0f); // restored
        out[2 * stride + rc] = fminf(fmaxf(red[3 + c],      0.0f), 1.0f); // direct
        out[3 * stride + rc] = fminf(fmaxf(bsr,             0.0f), 1.0f); // backscatter
    }
}

extern "C" void kernel_launch(void* const* d_in, const int* in_sizes, int n_in,
                              void* d_out, int out_size, void* d_ws, size_t ws_size,
                              hipStream_t stream) {
    const float* densities = (const float*)d_in[0];
    const float* rgbs      = (const float*)d_in[1];
    const float* veil      = (const float*)d_in[2];
    const float* dcoef     = (const float*)d_in[3];
    const float* bcoef     = (const float*)d_in[4];
    const float* deltas    = (const float*)d_in[5];
    float* out = (float*)d_out;

    const int R = in_sizes[0] / S;   // 65536
    dim3 grid((R + 7) / 8), block(256);
    uwnerf_render<<<grid, block, 0, stream>>>(densities, rgbs, veil, dcoef, bcoef,
                                              deltas, out, R);
}